// Round 1
// baseline (991.523 us; speedup 1.0000x reference)
//
#include <hip/hip_runtime.h>
#include <math.h>

#define B_  64
#define S_  2048
#define D_  512
#define NH_ 8

// ---------------- workspace layout (float offsets) ----------------
static const size_t OFF_WKEFF  = 0;                         // 8*512 = 4096
static const size_t OFF_SSUM   = 4096;                      // 64*512
static const size_t OFF_PSUM   = OFF_SSUM   + 32768;        // 64*512
static const size_t OFF_LSUM   = OFF_PSUM   + 32768;        // 64*8
static const size_t OFF_XAPART = OFF_LSUM   + 512;          // 64*16*4096
static const size_t OFF_XA     = OFF_XAPART + 4194304;      // 64*8*512
static const size_t OFF_FUSED  = OFF_XA     + 262144;       // 64*512
static const size_t OFF_FM     = OFF_FUSED  + 32768;
static const size_t OFF_MEANT  = OFF_FM     + 32768;
static const size_t OFF_CATSP  = OFF_MEANT  + 32768;        // 64*1024
static const size_t OFF_CLOST  = OFF_CATSP  + 65536;
static const size_t OFF_G1     = OFF_CLOST  + 32768;
static const size_t OFF_CTX    = OFF_G1     + 32768;
static const size_t OFF_HC     = OFF_CTX    + 32768;
static const size_t OFF_S3     = OFF_HC     + 32768;        // 64*4
static const size_t OFF_HEADIN = OFF_S3     + 256;          // 64*520 (stride 520, K=515)
static const size_t OFF_HS     = OFF_HEADIN + 33280;
static const size_t OFF_HF     = OFF_HS     + 32768;
static const size_t OFF_MINFO  = OFF_HF     + 32768;        // 64*8 ints

// ---------------- tiny utility kernels ----------------
__global__ __launch_bounds__(256) void k_zero(float* __restrict__ p, int n) {
    int i = blockIdx.x * 256 + threadIdx.x;
    if (i < n) p[i] = 0.f;
}

// wk_eff[h][e] = sum_d Wk[e, h*64+d] * q_tom[h, d] * (1/8)
__global__ __launch_bounds__(256) void k_wkeff(const float* __restrict__ Wk,
                                               const float* __restrict__ q,
                                               float* __restrict__ wkeff) {
    int idx = blockIdx.x * 256 + threadIdx.x;   // 4096
    int h = idx >> 9, e = idx & 511;
    float s = 0.f;
    #pragma unroll 8
    for (int d = 0; d < 64; ++d) s = fmaf(Wk[e * 512 + h * 64 + d], q[h * 64 + d], s);
    wkeff[h * 512 + e] = s * 0.125f;
}

// per-batch mask scan: total valid, split, boundary (s of split-th valid), last valid s
__global__ __launch_bounds__(256) void k_mask(const int* __restrict__ mask, int* __restrict__ minfo) {
    int b = blockIdx.x, tid = threadIdx.x;
    __shared__ int sh[256];
    int m8[8]; int cnt = 0; int s0 = tid * 8;
    #pragma unroll
    for (int i = 0; i < 8; ++i) { m8[i] = mask[b * S_ + s0 + i] > 0; cnt += m8[i]; }
    sh[tid] = cnt; __syncthreads();
    for (int off = 1; off < 256; off <<= 1) {
        int add = (tid >= off) ? sh[tid - off] : 0;
        __syncthreads();
        sh[tid] += add;
        __syncthreads();
    }
    int total  = sh[255];
    int before = sh[tid] - cnt;
    int split  = max(1, (int)floorf((float)total * 0.6f));
    int cum = before;
    #pragma unroll
    for (int i = 0; i < 8; ++i) {
        if (m8[i]) {
            cum++;
            if (cum == split) minfo[b * 8 + 2] = s0 + i;
            if (cum == total) minfo[b * 8 + 3] = s0 + i;
        }
    }
    if (tid == 0) { minfo[b * 8 + 0] = total; minfo[b * 8 + 1] = split; }
}

// ---------------- the single heavy pass over x ----------------
// Per block: batch b, 128 tokens (4 waves x 32). Lane owns 8 contiguous columns.
// Computes: unnormalized exp-weighted x sums per head (xapart), softmax denoms (lsum),
// and masked pooled sums (setup/punch) -- all in ONE read of x.
__global__ __launch_bounds__(256, 2) void k_main(const float* __restrict__ x,
                                                 const int* __restrict__ mask,
                                                 const float* __restrict__ wkeff,
                                                 const int* __restrict__ minfo,
                                                 float* __restrict__ ssum,
                                                 float* __restrict__ psum,
                                                 float* __restrict__ lsum,
                                                 float* __restrict__ xapart) {
    const int b = blockIdx.x, chunk = blockIdx.y;
    const int tid = threadIdx.x, wave = tid >> 6, lane = tid & 63;
    const int col0 = lane * 8;

    __shared__ float shx[4096];
    __shared__ float shs[512];
    __shared__ float shp[512];
    __shared__ float shl[8];
    for (int j = tid; j < 4096; j += 256) shx[j] = 0.f;
    shs[tid] = 0.f; shs[tid + 256] = 0.f;
    shp[tid] = 0.f; shp[tid + 256] = 0.f;
    if (tid < 8) shl[tid] = 0.f;
    __syncthreads();

    float wk[8][8];
    #pragma unroll
    for (int h = 0; h < 8; ++h)
        #pragma unroll
        for (int i = 0; i < 8; ++i) wk[h][i] = wkeff[h * 512 + col0 + i];

    const int boundary = minfo[b * 8 + 2];
    const float* xb = x + (size_t)b * S_ * D_;
    const int* mb = mask + b * S_;
    const int sb = chunk * 128 + wave * 32;

    // each lane<32 holds the mask of token sb+lane for this wave
    int mym = (lane < 32) ? mb[sb + lane] : 0;

    float xacc[8][8];
    #pragma unroll
    for (int h = 0; h < 8; ++h)
        #pragma unroll
        for (int i = 0; i < 8; ++i) xacc[h][i] = 0.f;
    float sacc[8], pacc[8], lacc[8];
    #pragma unroll
    for (int i = 0; i < 8; ++i) { sacc[i] = 0.f; pacc[i] = 0.f; lacc[i] = 0.f; }

    const float4* xp0 = (const float4*)(xb + (size_t)sb * D_ + col0);
    float4 A0 = xp0[0], A1 = xp0[1];

    for (int t = 0; t < 32; ++t) {
        float x8[8] = {A0.x, A0.y, A0.z, A0.w, A1.x, A1.y, A1.z, A1.w};
        if (t < 31) {
            const float4* np = (const float4*)(xb + (size_t)(sb + t + 1) * D_ + col0);
            A0 = np[0]; A1 = np[1];
        }
        // per-lane partial scores for the 8 heads
        float sc[8];
        #pragma unroll
        for (int h = 0; h < 8; ++h) {
            float a = x8[0] * wk[h][0];
            #pragma unroll
            for (int i = 1; i < 8; ++i) a = fmaf(x8[i], wk[h][i], a);
            sc[h] = a;
        }
        // all-reduce 8 values across 64 lanes (butterfly: every lane gets full sums)
        #pragma unroll
        for (int d = 1; d < 64; d <<= 1)
            #pragma unroll
            for (int h = 0; h < 8; ++h) sc[h] += __shfl_xor(sc[h], d, 64);

        int m = __shfl(mym, t, 64);
        int s = sb + t;
        bool isv = m > 0;
        bool iss = isv && (s <= boundary);
        bool isp = isv && (s > boundary);

        float w[8];
        #pragma unroll
        for (int h = 0; h < 8; ++h) w[h] = isv ? __expf(sc[h]) : 0.f;
        #pragma unroll
        for (int h = 0; h < 8; ++h) lacc[h] += w[h];

        float fs = iss ? 1.f : 0.f, fp = isp ? 1.f : 0.f;
        #pragma unroll
        for (int i = 0; i < 8; ++i) {
            sacc[i] = fmaf(x8[i], fs, sacc[i]);
            pacc[i] = fmaf(x8[i], fp, pacc[i]);
        }
        #pragma unroll
        for (int h = 0; h < 8; ++h)
            #pragma unroll
            for (int i = 0; i < 8; ++i) xacc[h][i] = fmaf(w[h], x8[i], xacc[h][i]);
    }

    // combine the 4 waves in LDS
    #pragma unroll
    for (int h = 0; h < 8; ++h)
        #pragma unroll
        for (int i = 0; i < 8; ++i) atomicAdd(&shx[h * 512 + col0 + i], xacc[h][i]);
    #pragma unroll
    for (int i = 0; i < 8; ++i) {
        atomicAdd(&shs[col0 + i], sacc[i]);
        atomicAdd(&shp[col0 + i], pacc[i]);
    }
    if (lane == 0) {
        #pragma unroll
        for (int h = 0; h < 8; ++h) atomicAdd(&shl[h], lacc[h]);  // lacc is lane-uniform
    }
    __syncthreads();

    float* dst = xapart + ((size_t)(b * 16 + chunk)) * 4096;
    for (int j = tid; j < 4096; j += 256) dst[j] = shx[j];
    atomicAdd(&ssum[b * 512 + tid],       shs[tid]);
    atomicAdd(&ssum[b * 512 + 256 + tid], shs[256 + tid]);
    atomicAdd(&psum[b * 512 + tid],       shp[tid]);
    atomicAdd(&psum[b * 512 + 256 + tid], shp[256 + tid]);
    if (tid < 8) atomicAdd(&lsum[b * 8 + tid], shl[tid]);
}

// xa[b][h][e] = (sum over 16 chunks of xapart) / l[b][h]
__global__ __launch_bounds__(256) void k_xared(const float* __restrict__ part,
                                               const float* __restrict__ lsum,
                                               float* __restrict__ xa) {
    int idx = blockIdx.x * 256 + threadIdx.x;   // 262144
    int b = idx >> 12, j = idx & 4095, h = j >> 9;
    float s = 0.f;
    #pragma unroll
    for (int c = 0; c < 16; ++c) s += part[((size_t)(b * 16 + c)) * 4096 + j];
    xa[idx] = s / lsum[b * 8 + h];
}

// fused[b, h*64+d] = xa[b,h,:] . Wv[:, h*64+d]
__global__ __launch_bounds__(256) void k_fused(const float* __restrict__ xa,
                                               const float* __restrict__ Wv,
                                               float* __restrict__ fused) {
    int b = blockIdx.x;
    int j = blockIdx.y * 256 + threadIdx.x;
    int h = j >> 6;
    const float* xr = xa + ((size_t)b * 8 + h) * 512;
    float s = 0.f;
    #pragma unroll 4
    for (int e = 0; e < 512; ++e) s = fmaf(xr[e], Wv[(size_t)e * 512 + j], s);
    fused[(size_t)b * 512 + j] = s;
}

// generic out[b][j] = act(A[b,:K] @ W[:,j] + bias[j]), N=512
__global__ __launch_bounds__(256) void k_dense(const float* __restrict__ A, int lda,
                                               const float* __restrict__ W,
                                               const float* __restrict__ bias,
                                               float* __restrict__ out,
                                               int K, int N, int relu_) {
    int b = blockIdx.x;
    int j = blockIdx.y * 256 + threadIdx.x;
    const float* a = A + (size_t)b * lda;
    float s = bias ? bias[j] : 0.f;
    int e = 0;
    for (; e + 4 <= K; e += 4) {
        s = fmaf(a[e],     W[(size_t)e * N + j], s);
        s = fmaf(a[e + 1], W[(size_t)(e + 1) * N + j], s);
        s = fmaf(a[e + 2], W[(size_t)(e + 2) * N + j], s);
        s = fmaf(a[e + 3], W[(size_t)(e + 3) * N + j], s);
    }
    for (; e < K; ++e) s = fmaf(a[e], W[(size_t)e * N + j], s);
    if (relu_) s = fmaxf(s, 0.f);
    out[(size_t)b * N + j] = s;
}

// mean_tok, setup_mean, punch_mean (w/ punch_cnt==0 fallback to last token), clost_stream
__global__ __launch_bounds__(256) void k_means(const float* __restrict__ x,
                                               const float* __restrict__ ssum,
                                               const float* __restrict__ psum,
                                               const int* __restrict__ minfo,
                                               float* __restrict__ meantok,
                                               float* __restrict__ catsp,
                                               float* __restrict__ clost) {
    int b = blockIdx.x;
    int e = blockIdx.y * 256 + threadIdx.x;
    int total = minfo[b * 8 + 0], split = minfo[b * 8 + 1], last = minfo[b * 8 + 3];
    int pcnt = total - split;
    float ssv = ssum[b * 512 + e], psv = psum[b * 512 + e];
    float mt = (ssv + psv) / (float)total;
    float sm = ssv / (float)split;
    float pm = (pcnt > 0) ? psv / (float)pcnt : x[((size_t)b * S_ + last) * D_ + e];
    meantok[b * 512 + e] = mt;
    catsp[b * 1024 + e] = sm;
    catsp[b * 1024 + 512 + e] = pm;
    clost[b * 512 + e] = 0.5f * (sm + pm);
}

// tom_hp, inc, clost_prob
__global__ __launch_bounds__(256) void k_scalars(const float* __restrict__ fm,
                                                 const float* __restrict__ ctx,
                                                 const float* __restrict__ hc,
                                                 const float* __restrict__ w_hp,  const float* __restrict__ b_hp,
                                                 const float* __restrict__ w_inc, const float* __restrict__ b_inc,
                                                 const float* __restrict__ wc2,   const float* __restrict__ bc2,
                                                 float* __restrict__ s3) {
    int b = blockIdx.x, tid = threadIdx.x;
    float a0 = 0.f, a1 = 0.f, a2 = 0.f;
    for (int e = tid; e < 512; e += 256) {
        a0 = fmaf(fm[b * 512 + e],  w_hp[e],  a0);
        a1 = fmaf(ctx[b * 512 + e], w_inc[e], a1);
        a2 = fmaf(hc[b * 512 + e],  wc2[e],   a2);
    }
    __shared__ float r[3][256];
    r[0][tid] = a0; r[1][tid] = a1; r[2][tid] = a2;
    __syncthreads();
    for (int off = 128; off > 0; off >>= 1) {
        if (tid < off) {
            r[0][tid] += r[0][tid + off];
            r[1][tid] += r[1][tid + off];
            r[2][tid] += r[2][tid + off];
        }
        __syncthreads();
    }
    if (tid == 0) {
        s3[b * 4 + 0] = 1.f / (1.f + __expf(-(r[0][0] + b_hp[0])));
        s3[b * 4 + 1] = 1.f / (1.f + __expf(-(r[1][0] + b_inc[0])));
        s3[b * 4 + 2] = 1.f / (1.f + __expf(-(r[2][0] + bc2[0])));
    }
}

// mixed = (I + U@V) @ streams, L2-normalize rows, pooled mean; build head_in=[pooled, scores3]
__global__ __launch_bounds__(256) void k_mix(const float* __restrict__ fm,
                                             const float* __restrict__ ctx,
                                             const float* __restrict__ clost,
                                             const float* __restrict__ U,
                                             const float* __restrict__ V,
                                             const float* __restrict__ s3,
                                             float* __restrict__ headin) {
    int b = blockIdx.x, tid = threadIdx.x;
    float M3[3][3];
    #pragma unroll
    for (int s = 0; s < 3; ++s)
        #pragma unroll
        for (int t = 0; t < 3; ++t) {
            float acc = (s == t) ? 1.f : 0.f;
            #pragma unroll
            for (int r4 = 0; r4 < 4; ++r4) acc = fmaf(U[s * 4 + r4], V[r4 * 3 + t], acc);
            M3[s][t] = acc;
        }
    float mx[3][2];
    #pragma unroll
    for (int kk = 0; kk < 2; ++kk) {
        int e = tid + kk * 256;
        float t0 = fm[b * 512 + e], t1 = ctx[b * 512 + e], t2 = clost[b * 512 + e];
        #pragma unroll
        for (int s = 0; s < 3; ++s) mx[s][kk] = M3[s][0] * t0 + M3[s][1] * t1 + M3[s][2] * t2;
    }
    __shared__ float r[3][256];
    #pragma unroll
    for (int s = 0; s < 3; ++s) r[s][tid] = mx[s][0] * mx[s][0] + mx[s][1] * mx[s][1];
    __syncthreads();
    for (int off = 128; off > 0; off >>= 1) {
        if (tid < off) {
            r[0][tid] += r[0][tid + off];
            r[1][tid] += r[1][tid + off];
            r[2][tid] += r[2][tid + off];
        }
        __syncthreads();
    }
    __shared__ float nrm[3];
    if (tid < 3) nrm[tid] = sqrtf(r[tid][0]) + 1e-6f;
    __syncthreads();
    #pragma unroll
    for (int kk = 0; kk < 2; ++kk) {
        int e = tid + kk * 256;
        float p = (mx[0][kk] / nrm[0] + mx[1][kk] / nrm[1] + mx[2][kk] / nrm[2]) * (1.f / 3.f);
        headin[b * 520 + e] = p;
    }
    if (tid < 3) headin[b * 520 + 512 + tid] = s3[b * 4 + tid];
}

__global__ __launch_bounds__(256) void k_logit(const float* __restrict__ hs,
                                               const float* __restrict__ hf,
                                               const float* __restrict__ ws2, const float* __restrict__ bs2,
                                               const float* __restrict__ wf2, const float* __restrict__ bf2,
                                               const float* __restrict__ s3,
                                               float* __restrict__ out) {
    int b = blockIdx.x, tid = threadIdx.x;
    float a = 0.f, c = 0.f;
    for (int e = tid; e < 512; e += 256) {
        a = fmaf(hs[b * 512 + e], ws2[e], a);
        c = fmaf(hf[b * 512 + e], wf2[e], c);
    }
    __shared__ float r[2][256];
    r[0][tid] = a; r[1][tid] = c;
    __syncthreads();
    for (int off = 128; off > 0; off >>= 1) {
        if (tid < off) { r[0][tid] += r[0][tid + off]; r[1][tid] += r[1][tid + off]; }
        __syncthreads();
    }
    if (tid == 0) {
        float sev = r[0][0] + bs2[0];
        float fl  = r[1][0] + bf2[0];
        float p = (s3[b * 4] + s3[b * 4 + 1] + s3[b * 4 + 2]) * (1.f / 3.f);
        p = fminf(fmaxf(p, 1e-4f), 1.f - 1e-4f);
        out[b] = fl + 0.5f * sev + 0.1f * logf(p / (1.f - p));
    }
}

extern "C" void kernel_launch(void* const* d_in, const int* in_sizes, int n_in,
                              void* d_out, int out_size, void* d_ws, size_t ws_size,
                              hipStream_t stream) {
    const float* x     = (const float*)d_in[0];
    const int*   mask  = (const int*)d_in[1];
    const float* Wk    = (const float*)d_in[2];
    const float* Wv    = (const float*)d_in[3];
    const float* q_tom = (const float*)d_in[4];
    const float* Wtf   = (const float*)d_in[5];
    const float* w_hp  = (const float*)d_in[6];
    const float* b_hp  = (const float*)d_in[7];
    const float* Wg1   = (const float*)d_in[8];
    const float* bg1   = (const float*)d_in[9];
    const float* Wg2   = (const float*)d_in[10];
    const float* bg2   = (const float*)d_in[11];
    const float* w_inc = (const float*)d_in[12];
    const float* b_inc = (const float*)d_in[13];
    const float* Wc1   = (const float*)d_in[14];
    const float* bc1   = (const float*)d_in[15];
    const float* wc2   = (const float*)d_in[16];
    const float* bc2   = (const float*)d_in[17];
    const float* U     = (const float*)d_in[18];
    const float* V     = (const float*)d_in[19];
    const float* Ws1   = (const float*)d_in[20];
    const float* bs1   = (const float*)d_in[21];
    const float* ws2   = (const float*)d_in[22];
    const float* bs2   = (const float*)d_in[23];
    const float* Wf1   = (const float*)d_in[24];
    const float* bf1   = (const float*)d_in[25];
    const float* wf2   = (const float*)d_in[26];
    const float* bf2   = (const float*)d_in[27];

    float* ws      = (float*)d_ws;
    float* wkeff   = ws + OFF_WKEFF;
    float* ssum    = ws + OFF_SSUM;
    float* psum    = ws + OFF_PSUM;
    float* lsum    = ws + OFF_LSUM;
    float* xapart  = ws + OFF_XAPART;
    float* xa      = ws + OFF_XA;
    float* fused   = ws + OFF_FUSED;
    float* fm      = ws + OFF_FM;
    float* meantok = ws + OFF_MEANT;
    float* catsp   = ws + OFF_CATSP;
    float* clost   = ws + OFF_CLOST;
    float* g1      = ws + OFF_G1;
    float* ctxb    = ws + OFF_CTX;
    float* hc      = ws + OFF_HC;
    float* s3      = ws + OFF_S3;
    float* headin  = ws + OFF_HEADIN;
    float* hsb     = ws + OFF_HS;
    float* hfb     = ws + OFF_HF;
    int*   minfo   = (int*)(ws + OFF_MINFO);
    float* out     = (float*)d_out;

    hipLaunchKernelGGL(k_zero,   dim3(258),    dim3(256), 0, stream, ssum, 66048); // ssum+psum+lsum
    hipLaunchKernelGGL(k_wkeff,  dim3(16),     dim3(256), 0, stream, Wk, q_tom, wkeff);
    hipLaunchKernelGGL(k_mask,   dim3(64),     dim3(256), 0, stream, mask, minfo);
    hipLaunchKernelGGL(k_main,   dim3(64, 16), dim3(256), 0, stream, x, mask, wkeff, minfo,
                       ssum, psum, lsum, xapart);
    hipLaunchKernelGGL(k_xared,  dim3(1024),   dim3(256), 0, stream, xapart, lsum, xa);
    hipLaunchKernelGGL(k_fused,  dim3(64, 2),  dim3(256), 0, stream, xa, Wv, fused);
    hipLaunchKernelGGL(k_dense,  dim3(64, 2),  dim3(256), 0, stream, fused, 512, Wtf,
                       (const float*)nullptr, fm, 512, 512, 0);
    hipLaunchKernelGGL(k_means,  dim3(64, 2),  dim3(256), 0, stream, x, ssum, psum, minfo,
                       meantok, catsp, clost);
    hipLaunchKernelGGL(k_dense,  dim3(64, 2),  dim3(256), 0, stream, meantok, 512, Wg1, bg1, g1, 512, 512, 1);
    hipLaunchKernelGGL(k_dense,  dim3(64, 2),  dim3(256), 0, stream, g1, 512, Wg2, bg2, ctxb, 512, 512, 0);
    hipLaunchKernelGGL(k_dense,  dim3(64, 2),  dim3(256), 0, stream, catsp, 1024, Wc1, bc1, hc, 1024, 512, 1);
    hipLaunchKernelGGL(k_scalars,dim3(64),     dim3(256), 0, stream, fm, ctxb, hc,
                       w_hp, b_hp, w_inc, b_inc, wc2, bc2, s3);
    hipLaunchKernelGGL(k_mix,    dim3(64),     dim3(256), 0, stream, fm, ctxb, clost, U, V, s3, headin);
    hipLaunchKernelGGL(k_dense,  dim3(64, 2),  dim3(256), 0, stream, headin, 520, Ws1, bs1, hsb, 515, 512, 1);
    hipLaunchKernelGGL(k_dense,  dim3(64, 2),  dim3(256), 0, stream, headin, 520, Wf1, bf1, hfb, 515, 512, 1);
    hipLaunchKernelGGL(k_logit,  dim3(64),     dim3(256), 0, stream, hsb, hfb, ws2, bs2, wf2, bf2, s3, out);
}

// Round 2
// 510.909 us; speedup vs baseline: 1.9407x; 1.9407x over previous
//
#include <hip/hip_runtime.h>
#include <math.h>

#define B_  64
#define S_  2048
#define D_  512
#define NH_ 8

// ---------------- workspace layout (float offsets) ----------------
static const size_t OFF_WKEFF  = 0;                         // 8*512 = 4096
static const size_t OFF_SSUM   = 4096;                      // 64*512
static const size_t OFF_PSUM   = OFF_SSUM   + 32768;        // 64*512
static const size_t OFF_LSUM   = OFF_PSUM   + 32768;        // 64*8
static const size_t OFF_XAPART = OFF_LSUM   + 512;          // 64*16*4096 = 16 MB
static const size_t OFF_XA     = OFF_XAPART + 4194304;      // 64*8*512
static const size_t OFF_FUSED  = OFF_XA     + 262144;       // 64*512
static const size_t OFF_FM     = OFF_FUSED  + 32768;
static const size_t OFF_MEANT  = OFF_FM     + 32768;
static const size_t OFF_CATSP  = OFF_MEANT  + 32768;        // 64*1024
static const size_t OFF_CLOST  = OFF_CATSP  + 65536;
static const size_t OFF_G1     = OFF_CLOST  + 32768;
static const size_t OFF_CTX    = OFF_G1     + 32768;
static const size_t OFF_HC     = OFF_CTX    + 32768;
static const size_t OFF_S3     = OFF_HC     + 32768;        // 64*4
static const size_t OFF_HEADIN = OFF_S3     + 256;          // 64*520 (stride 520, K=515)
static const size_t OFF_HS     = OFF_HEADIN + 33280;
static const size_t OFF_HF     = OFF_HS     + 32768;
static const size_t OFF_MINFO  = OFF_HF     + 32768;        // 64*8 ints

// ---------------- fused prep: zero accumulators + wkeff + mask scan ----------------
// blocks [0,258): zero ssum/psum/lsum (66048 floats, contiguous)
// blocks [258,274): wkeff (4096 elems)
// blocks [274,338): per-batch mask scan
__global__ __launch_bounds__(256) void k_prep(const float* __restrict__ Wk,
                                              const float* __restrict__ q,
                                              const int* __restrict__ mask,
                                              float* __restrict__ zbase,   // ssum (psum/lsum follow)
                                              float* __restrict__ wkeff,
                                              int* __restrict__ minfo) {
    int bx = blockIdx.x, tid = threadIdx.x;
    if (bx < 258) {
        int i = bx * 256 + tid;
        if (i < 66048) zbase[i] = 0.f;
        return;
    }
    if (bx < 274) {
        int idx = (bx - 258) * 256 + tid;       // [0,4096)
        int h = idx >> 9, e = idx & 511;
        float s = 0.f;
        #pragma unroll 8
        for (int d = 0; d < 64; ++d) s = fmaf(Wk[e * 512 + h * 64 + d], q[h * 64 + d], s);
        wkeff[h * 512 + e] = s * 0.125f;
        return;
    }
    {
        int b = bx - 274;
        __shared__ int sh[256];
        int m8[8]; int cnt = 0; int s0 = tid * 8;
        #pragma unroll
        for (int i = 0; i < 8; ++i) { m8[i] = mask[b * S_ + s0 + i] > 0; cnt += m8[i]; }
        sh[tid] = cnt; __syncthreads();
        for (int off = 1; off < 256; off <<= 1) {
            int add = (tid >= off) ? sh[tid - off] : 0;
            __syncthreads();
            sh[tid] += add;
            __syncthreads();
        }
        int total  = sh[255];
        int before = sh[tid] - cnt;
        int split  = max(1, (int)floorf((float)total * 0.6f));
        int cum = before;
        #pragma unroll
        for (int i = 0; i < 8; ++i) {
            if (m8[i]) {
                cum++;
                if (cum == split) minfo[b * 8 + 2] = s0 + i;
                if (cum == total) minfo[b * 8 + 3] = s0 + i;
            }
        }
        if (tid == 0) { minfo[b * 8 + 0] = total; minfo[b * 8 + 1] = split; }
    }
}

// ---------------- single heavy pass over x ----------------
// grid (64, 16). Block = 128 tokens. 4 waves all read the SAME tokens
// (wave 2..4 reads hit L1); wave w owns heads {2w, 2w+1}. Lane owns 8 cols.
// Per wave: wk 2x8 + xacc 2x8 regs only -> ~100 VGPR, 4 waves/SIMD.
// Tokens processed in PAIRS with one-pair prefetch (8 loads in flight).
// No LDS at all: each wave stores its own 2 head-rows of xapart; wave 0
// additionally accumulates setup/punch sums (global atomics, once per block).
__global__ __launch_bounds__(256, 4) void k_main(const float* __restrict__ x,
                                                 const int* __restrict__ mask,
                                                 const float* __restrict__ wkeff,
                                                 const int* __restrict__ minfo,
                                                 float* __restrict__ ssum,
                                                 float* __restrict__ psum,
                                                 float* __restrict__ lsum,
                                                 float* __restrict__ xapart) {
    const int b = blockIdx.x, chunk = blockIdx.y;
    const int tid = threadIdx.x, hg = tid >> 6, lane = tid & 63;
    const int h0 = hg * 2;
    const int col0 = lane * 8;

    float wk0[8], wk1[8];
    #pragma unroll
    for (int i = 0; i < 8; ++i) {
        wk0[i] = wkeff[h0 * 512 + col0 + i];
        wk1[i] = wkeff[(h0 + 1) * 512 + col0 + i];
    }

    const int boundary = minfo[b * 8 + 2];
    const float* xb = x + (size_t)b * (S_ * D_);
    const int* mb = mask + b * S_;
    const int sb = chunk * 128;

    int m0 = mb[sb + lane];
    int m1 = mb[sb + 64 + lane];

    float xacc0[8], xacc1[8], sacc[8], pacc[8];
    #pragma unroll
    for (int i = 0; i < 8; ++i) { xacc0[i] = 0.f; xacc1[i] = 0.f; sacc[i] = 0.f; pacc[i] = 0.f; }
    float lacc0 = 0.f, lacc1 = 0.f;

    const float* base = xb + (size_t)sb * D_ + col0;
    float4 A0 = *(const float4*)(base);
    float4 A1 = *(const float4*)(base + 4);
    float4 B0 = *(const float4*)(base + D_);
    float4 B1 = *(const float4*)(base + D_ + 4);

    for (int t = 0; t < 128; t += 2) {
        float xa8[8] = {A0.x, A0.y, A0.z, A0.w, A1.x, A1.y, A1.z, A1.w};
        float xb8[8] = {B0.x, B0.y, B0.z, B0.w, B1.x, B1.y, B1.z, B1.w};
        if (t + 2 < 128) {
            const float* nb = base + (size_t)(t + 2) * D_;
            A0 = *(const float4*)(nb);
            A1 = *(const float4*)(nb + 4);
            B0 = *(const float4*)(nb + D_);
            B1 = *(const float4*)(nb + D_ + 4);
        }
        // per-lane partial scores: 2 heads x 2 tokens
        float s00 = xa8[0] * wk0[0], s01 = xa8[0] * wk1[0];
        float s10 = xb8[0] * wk0[0], s11 = xb8[0] * wk1[0];
        #pragma unroll
        for (int i = 1; i < 8; ++i) {
            s00 = fmaf(xa8[i], wk0[i], s00);
            s01 = fmaf(xa8[i], wk1[i], s01);
            s10 = fmaf(xb8[i], wk0[i], s10);
            s11 = fmaf(xb8[i], wk1[i], s11);
        }
        // 4 interleaved butterflies across 64 lanes
        #pragma unroll
        for (int d = 1; d < 64; d <<= 1) {
            s00 += __shfl_xor(s00, d, 64);
            s01 += __shfl_xor(s01, d, 64);
            s10 += __shfl_xor(s10, d, 64);
            s11 += __shfl_xor(s11, d, 64);
        }
        int mreg = (t & 64) ? m1 : m0;
        int mm0 = __shfl(mreg, t & 63, 64);
        int mm1 = __shfl(mreg, (t + 1) & 63, 64);
        int sg0 = sb + t, sg1 = sb + t + 1;

        float w00 = (mm0 > 0) ? __expf(s00) : 0.f;
        float w01 = (mm0 > 0) ? __expf(s01) : 0.f;
        float w10 = (mm1 > 0) ? __expf(s10) : 0.f;
        float w11 = (mm1 > 0) ? __expf(s11) : 0.f;
        lacc0 += w00 + w10;
        lacc1 += w01 + w11;
        #pragma unroll
        for (int i = 0; i < 8; ++i) {
            xacc0[i] = fmaf(w10, xb8[i], fmaf(w00, xa8[i], xacc0[i]));
            xacc1[i] = fmaf(w11, xb8[i], fmaf(w01, xa8[i], xacc1[i]));
        }
        if (hg == 0) {
            float fs0 = (mm0 > 0 && sg0 <= boundary) ? 1.f : 0.f;
            float fp0 = (mm0 > 0 && sg0 >  boundary) ? 1.f : 0.f;
            float fs1 = (mm1 > 0 && sg1 <= boundary) ? 1.f : 0.f;
            float fp1 = (mm1 > 0 && sg1 >  boundary) ? 1.f : 0.f;
            #pragma unroll
            for (int i = 0; i < 8; ++i) {
                sacc[i] = fmaf(fs1, xb8[i], fmaf(fs0, xa8[i], sacc[i]));
                pacc[i] = fmaf(fp1, xb8[i], fmaf(fp0, xa8[i], pacc[i]));
            }
        }
    }

    // direct stores: wave owns its 2 head rows exclusively
    float* d0 = xapart + (((size_t)b * 16 + chunk) * 8 + h0) * 512 + col0;
    float* d1 = d0 + 512;
    ((float4*)d0)[0] = make_float4(xacc0[0], xacc0[1], xacc0[2], xacc0[3]);
    ((float4*)d0)[1] = make_float4(xacc0[4], xacc0[5], xacc0[6], xacc0[7]);
    ((float4*)d1)[0] = make_float4(xacc1[0], xacc1[1], xacc1[2], xacc1[3]);
    ((float4*)d1)[1] = make_float4(xacc1[4], xacc1[5], xacc1[6], xacc1[7]);
    if (lane == 0) {
        atomicAdd(&lsum[b * 8 + h0],     lacc0);
        atomicAdd(&lsum[b * 8 + h0 + 1], lacc1);
    }
    if (hg == 0) {
        #pragma unroll
        for (int i = 0; i < 8; ++i) {
            atomicAdd(&ssum[b * 512 + col0 + i], sacc[i]);
            atomicAdd(&psum[b * 512 + col0 + i], pacc[i]);
        }
    }
}

// xa[b][h][e] = (sum over 16 chunks of xapart) / l[b][h]
__global__ __launch_bounds__(256) void k_xared(const float* __restrict__ part,
                                               const float* __restrict__ lsum,
                                               float* __restrict__ xa) {
    int idx = blockIdx.x * 256 + threadIdx.x;   // 262144
    int b = idx >> 12, j = idx & 4095, h = j >> 9;
    float s = 0.f;
    #pragma unroll
    for (int c = 0; c < 16; ++c) s += part[((size_t)(b * 16 + c)) * 4096 + j];
    xa[idx] = s / lsum[b * 8 + h];
}

// mean_tok, setup_mean, punch_mean (punch_cnt==0 -> last valid token), clost_stream
__global__ __launch_bounds__(256) void k_means(const float* __restrict__ x,
                                               const float* __restrict__ ssum,
                                               const float* __restrict__ psum,
                                               const int* __restrict__ minfo,
                                               float* __restrict__ meantok,
                                               float* __restrict__ catsp,
                                               float* __restrict__ clost) {
    int b = blockIdx.x;
    int e = blockIdx.y * 256 + threadIdx.x;
    int total = minfo[b * 8 + 0], split = minfo[b * 8 + 1], last = minfo[b * 8 + 3];
    int pcnt = total - split;
    float ssv = ssum[b * 512 + e], psv = psum[b * 512 + e];
    float mt = (ssv + psv) / (float)total;
    float sm = ssv / (float)split;
    float pm = (pcnt > 0) ? psv / (float)pcnt : x[((size_t)b * S_ + last) * D_ + e];
    meantok[b * 512 + e] = mt;
    catsp[b * 1024 + e] = sm;
    catsp[b * 1024 + 512 + e] = pm;
    clost[b * 512 + e] = 0.5f * (sm + pm);
}

// ---------------- batched GEMV: up to 3 ops per launch (blockIdx.z) ----------------
// grid (64, 8, nz). Block: batch b, 64 outputs, 4-way K-split (256 thr).
// A row staged in LDS; W loads coalesced (64 consecutive j per wave-quarter),
// 8-deep unrolled independent loads for MLP. headmode: A row = xa[b, head(jg)].
__global__ __launch_bounds__(256) void k_gemv3(
    const float* A0_, int lda0, const float* W0_, const float* bi0_, float* o0_, int K0, int r0, int hm0,
    const float* A1_, int lda1, const float* W1_, const float* bi1_, float* o1_, int K1, int r1, int hm1,
    const float* A2_, int lda2, const float* W2_, const float* bi2_, float* o2_, int K2, int r2, int hm2) {
    const float* A; const float* W; const float* bias; float* out;
    int lda, K, relu_, hm;
    int z = blockIdx.z;
    if (z == 0)      { A = A0_; lda = lda0; W = W0_; bias = bi0_; out = o0_; K = K0; relu_ = r0; hm = hm0; }
    else if (z == 1) { A = A1_; lda = lda1; W = W1_; bias = bi1_; out = o1_; K = K1; relu_ = r1; hm = hm1; }
    else             { A = A2_; lda = lda2; W = W2_; bias = bi2_; out = o2_; K = K2; relu_ = r2; hm = hm2; }

    int b = blockIdx.x, jg = blockIdx.y;
    int tid = threadIdx.x, jl = tid & 63, part = tid >> 6;
    int j = jg * 64 + jl;
    const float* a = hm ? (A + ((size_t)(b * 8 + jg)) * 512) : (A + (size_t)b * lda);

    __shared__ float sha[1024];
    for (int e = tid; e < K; e += 256) sha[e] = a[e];
    __syncthreads();

    int Kq = (K + 3) >> 2;
    int e0 = part * Kq, e1 = min(K, e0 + Kq);
    float acc = 0.f;
    int e = e0;
    for (; e + 8 <= e1; e += 8) {
        #pragma unroll
        for (int u = 0; u < 8; ++u)
            acc = fmaf(sha[e + u], W[(size_t)(e + u) * 512 + j], acc);
    }
    for (; e < e1; ++e) acc = fmaf(sha[e], W[(size_t)e * 512 + j], acc);

    __shared__ float shr[256];
    shr[tid] = acc;
    __syncthreads();
    if (part == 0) {
        float s = shr[jl] + shr[jl + 64] + shr[jl + 128] + shr[jl + 192];
        if (bias) s += bias[j];
        if (relu_) s = fmaxf(s, 0.f);
        out[(size_t)b * 512 + j] = s;
    }
}

// fused: scalar heads (tom_hp/inc/clost_prob) + stream mixing + headin build
__global__ __launch_bounds__(256) void k_scalmix(const float* __restrict__ fm,
                                                 const float* __restrict__ ctx,
                                                 const float* __restrict__ hc,
                                                 const float* __restrict__ clost,
                                                 const float* __restrict__ w_hp,  const float* __restrict__ b_hp,
                                                 const float* __restrict__ w_inc, const float* __restrict__ b_inc,
                                                 const float* __restrict__ wc2,   const float* __restrict__ bc2,
                                                 const float* __restrict__ U,
                                                 const float* __restrict__ V,
                                                 float* __restrict__ s3,
                                                 float* __restrict__ headin) {
    int b = blockIdx.x, tid = threadIdx.x;
    // --- scalars ---
    float a0 = 0.f, a1 = 0.f, a2 = 0.f;
    for (int e = tid; e < 512; e += 256) {
        a0 = fmaf(fm[b * 512 + e],  w_hp[e],  a0);
        a1 = fmaf(ctx[b * 512 + e], w_inc[e], a1);
        a2 = fmaf(hc[b * 512 + e],  wc2[e],   a2);
    }
    __shared__ float r[3][256];
    r[0][tid] = a0; r[1][tid] = a1; r[2][tid] = a2;
    __syncthreads();
    for (int off = 128; off > 0; off >>= 1) {
        if (tid < off) {
            r[0][tid] += r[0][tid + off];
            r[1][tid] += r[1][tid + off];
            r[2][tid] += r[2][tid + off];
        }
        __syncthreads();
    }
    __shared__ float s3sh[3];
    if (tid == 0) {
        s3sh[0] = 1.f / (1.f + __expf(-(r[0][0] + b_hp[0])));
        s3sh[1] = 1.f / (1.f + __expf(-(r[1][0] + b_inc[0])));
        s3sh[2] = 1.f / (1.f + __expf(-(r[2][0] + bc2[0])));
        s3[b * 4 + 0] = s3sh[0];
        s3[b * 4 + 1] = s3sh[1];
        s3[b * 4 + 2] = s3sh[2];
    }
    __syncthreads();
    // --- mix ---
    float M3[3][3];
    #pragma unroll
    for (int s = 0; s < 3; ++s)
        #pragma unroll
        for (int t = 0; t < 3; ++t) {
            float acc = (s == t) ? 1.f : 0.f;
            #pragma unroll
            for (int r4 = 0; r4 < 4; ++r4) acc = fmaf(U[s * 4 + r4], V[r4 * 3 + t], acc);
            M3[s][t] = acc;
        }
    float mx[3][2];
    #pragma unroll
    for (int kk = 0; kk < 2; ++kk) {
        int e = tid + kk * 256;
        float t0 = fm[b * 512 + e], t1 = ctx[b * 512 + e], t2 = clost[b * 512 + e];
        #pragma unroll
        for (int s = 0; s < 3; ++s) mx[s][kk] = M3[s][0] * t0 + M3[s][1] * t1 + M3[s][2] * t2;
    }
    #pragma unroll
    for (int s = 0; s < 3; ++s) r[s][tid] = mx[s][0] * mx[s][0] + mx[s][1] * mx[s][1];
    __syncthreads();
    for (int off = 128; off > 0; off >>= 1) {
        if (tid < off) {
            r[0][tid] += r[0][tid + off];
            r[1][tid] += r[1][tid + off];
            r[2][tid] += r[2][tid + off];
        }
        __syncthreads();
    }
    __shared__ float nrm[3];
    if (tid < 3) nrm[tid] = sqrtf(r[tid][0]) + 1e-6f;
    __syncthreads();
    #pragma unroll
    for (int kk = 0; kk < 2; ++kk) {
        int e = tid + kk * 256;
        float p = (mx[0][kk] / nrm[0] + mx[1][kk] / nrm[1] + mx[2][kk] / nrm[2]) * (1.f / 3.f);
        headin[b * 520 + e] = p;
    }
    if (tid < 3) headin[b * 520 + 512 + tid] = s3sh[tid];
}

__global__ __launch_bounds__(256) void k_logit(const float* __restrict__ hs,
                                               const float* __restrict__ hf,
                                               const float* __restrict__ ws2, const float* __restrict__ bs2,
                                               const float* __restrict__ wf2, const float* __restrict__ bf2,
                                               const float* __restrict__ s3,
                                               float* __restrict__ out) {
    int b = blockIdx.x, tid = threadIdx.x;
    float a = 0.f, c = 0.f;
    for (int e = tid; e < 512; e += 256) {
        a = fmaf(hs[b * 512 + e], ws2[e], a);
        c = fmaf(hf[b * 512 + e], wf2[e], c);
    }
    __shared__ float r[2][256];
    r[0][tid] = a; r[1][tid] = c;
    __syncthreads();
    for (int off = 128; off > 0; off >>= 1) {
        if (tid < off) { r[0][tid] += r[0][tid + off]; r[1][tid] += r[1][tid + off]; }
        __syncthreads();
    }
    if (tid == 0) {
        float sev = r[0][0] + bs2[0];
        float fl  = r[1][0] + bf2[0];
        float p = (s3[b * 4] + s3[b * 4 + 1] + s3[b * 4 + 2]) * (1.f / 3.f);
        p = fminf(fmaxf(p, 1e-4f), 1.f - 1e-4f);
        out[b] = fl + 0.5f * sev + 0.1f * logf(p / (1.f - p));
    }
}

extern "C" void kernel_launch(void* const* d_in, const int* in_sizes, int n_in,
                              void* d_out, int out_size, void* d_ws, size_t ws_size,
                              hipStream_t stream) {
    const float* x     = (const float*)d_in[0];
    const int*   mask  = (const int*)d_in[1];
    const float* Wk    = (const float*)d_in[2];
    const float* Wv    = (const float*)d_in[3];
    const float* q_tom = (const float*)d_in[4];
    const float* Wtf   = (const float*)d_in[5];
    const float* w_hp  = (const float*)d_in[6];
    const float* b_hp  = (const float*)d_in[7];
    const float* Wg1   = (const float*)d_in[8];
    const float* bg1   = (const float*)d_in[9];
    const float* Wg2   = (const float*)d_in[10];
    const float* bg2   = (const float*)d_in[11];
    const float* w_inc = (const float*)d_in[12];
    const float* b_inc = (const float*)d_in[13];
    const float* Wc1   = (const float*)d_in[14];
    const float* bc1   = (const float*)d_in[15];
    const float* wc2   = (const float*)d_in[16];
    const float* bc2   = (const float*)d_in[17];
    const float* U     = (const float*)d_in[18];
    const float* V     = (const float*)d_in[19];
    const float* Ws1   = (const float*)d_in[20];
    const float* bs1   = (const float*)d_in[21];
    const float* ws2   = (const float*)d_in[22];
    const float* bs2   = (const float*)d_in[23];
    const float* Wf1   = (const float*)d_in[24];
    const float* bf1   = (const float*)d_in[25];
    const float* wf2   = (const float*)d_in[26];
    const float* bf2   = (const float*)d_in[27];

    float* ws      = (float*)d_ws;
    float* wkeff   = ws + OFF_WKEFF;
    float* ssum    = ws + OFF_SSUM;
    float* psum    = ws + OFF_PSUM;
    float* lsum    = ws + OFF_LSUM;
    float* xapart  = ws + OFF_XAPART;
    float* xa      = ws + OFF_XA;
    float* fused   = ws + OFF_FUSED;
    float* fm      = ws + OFF_FM;
    float* meantok = ws + OFF_MEANT;
    float* catsp   = ws + OFF_CATSP;
    float* clost   = ws + OFF_CLOST;
    float* g1      = ws + OFF_G1;
    float* ctxb    = ws + OFF_CTX;
    float* hc      = ws + OFF_HC;
    float* s3      = ws + OFF_S3;
    float* headin  = ws + OFF_HEADIN;
    float* hsb     = ws + OFF_HS;
    float* hfb     = ws + OFF_HF;
    int*   minfo   = (int*)(ws + OFF_MINFO);
    float* out     = (float*)d_out;

    hipLaunchKernelGGL(k_prep,   dim3(338),      dim3(256), 0, stream, Wk, q_tom, mask, ssum, wkeff, minfo);
    hipLaunchKernelGGL(k_main,   dim3(64, 16),   dim3(256), 0, stream, x, mask, wkeff, minfo,
                       ssum, psum, lsum, xapart);
    hipLaunchKernelGGL(k_xared,  dim3(1024),     dim3(256), 0, stream, xapart, lsum, xa);
    hipLaunchKernelGGL(k_means,  dim3(64, 2),    dim3(256), 0, stream, x, ssum, psum, minfo,
                       meantok, catsp, clost);
    // stage A: fused = xa(head)@Wv ; g1 = relu(meantok@Wg1+bg1) ; hc = relu(catsp@Wc1+bc1)
    hipLaunchKernelGGL(k_gemv3,  dim3(64, 8, 3), dim3(256), 0, stream,
                       xa, 0, Wv, (const float*)nullptr, fused, 512, 0, 1,
                       meantok, 512, Wg1, bg1, g1, 512, 1, 0,
                       catsp, 1024, Wc1, bc1, hc, 1024, 1, 0);
    // stage B: fm = fused@Wtf ; ctx = g1@Wg2+bg2
    hipLaunchKernelGGL(k_gemv3,  dim3(64, 8, 2), dim3(256), 0, stream,
                       fused, 512, Wtf, (const float*)nullptr, fm, 512, 0, 0,
                       g1, 512, Wg2, bg2, ctxb, 512, 0, 0,
                       (const float*)nullptr, 0, (const float*)nullptr, (const float*)nullptr,
                       (float*)nullptr, 0, 0, 0);
    hipLaunchKernelGGL(k_scalmix, dim3(64),      dim3(256), 0, stream, fm, ctxb, hc, clost,
                       w_hp, b_hp, w_inc, b_inc, wc2, bc2, U, V, s3, headin);
    // stage D: hs = relu(headin@Ws1+bs1) ; hf = relu(headin@Wf1+bf1)  (K=515, lda=520)
    hipLaunchKernelGGL(k_gemv3,  dim3(64, 8, 2), dim3(256), 0, stream,
                       headin, 520, Ws1, bs1, hsb, 515, 1, 0,
                       headin, 520, Wf1, bf1, hfb, 515, 1, 0,
                       (const float*)nullptr, 0, (const float*)nullptr, (const float*)nullptr,
                       (float*)nullptr, 0, 0, 0);
    hipLaunchKernelGGL(k_logit,  dim3(64),       dim3(256), 0, stream, hsb, hfb, ws2, bs2, wf2, bf2, s3, out);
}